// Round 3
// baseline (104.209 us; speedup 1.0000x reference)
//
#include <hip/hip_runtime.h>
#include <math.h>

// Problem constants (from the reference):
//  levels: (64,64,s=8,bs=32) (32,32,s=16,bs=64) (16,16,s=32,bs=128) (8,8,s=64,bs=256)
//  K = 9 anchors/position (3 ratios x 3 scales), A = 48960, B = 16, M = 64 GT boxes
#define A_TOTAL 48960
#define A_HALF  24480
#define M_GT    64
#define B_BATCH 16

// Pack per-batch GT data for wave-uniform scalar-pipe reads in the main loop:
// (B, 64, 8) floats = {x1, y1, x2, y2, area, label, 0, 0}  (32 B -> s_load_dwordx8)
__global__ __launch_bounds__(64) void prep_kernel(
    const float* __restrict__ gt_boxes, const int* __restrict__ gt_labels,
    float* __restrict__ prep)
{
    const int t = blockIdx.x * 64 + threadIdx.x;       // 0 .. B*M-1
    const float4 g = ((const float4*)gt_boxes)[t];
    const float area = (g.z - g.x) * (g.w - g.y);      // same op order as ref
    const float lab  = (float)gt_labels[t];
    float4* p = (float4*)(prep + (size_t)t * 8);
    p[0] = g;
    p[1] = make_float4(area, lab, 0.0f, 0.0f);
}

__global__ __launch_bounds__(256) void anchors_assign_kernel(
    const float* __restrict__ gt_boxes,   // (B, 64, 4) xyxy
    const int*   __restrict__ gt_labels,  // (B, 64)
    const float* __restrict__ prep,       // (B, 64, 8) packed, read scalar
    float* __restrict__ out_loc,          // (B, A, 4)
    float* __restrict__ out_cls)          // (B, A)
{
    __shared__ float4 sbox[M_GT];         // for the divergent epilogue gather only
    __shared__ float  sarea[M_GT];
    __shared__ float  slab[M_GT];

    const int b   = blockIdx.y;
    const int tid = threadIdx.x;

    if (tid < M_GT) {
        float4 g = ((const float4*)gt_boxes)[b * M_GT + tid];
        sbox[tid]  = g;
        sarea[tid] = (g.z - g.x) * (g.w - g.y);
        slab[tid]  = (float)gt_labels[b * M_GT + tid];
    }
    __syncthreads();

    const int a0 = blockIdx.x * 256 + tid;   // anchor 1; anchor 2 = a0 + A_HALF
    if (a0 >= A_HALF) return;

    // Per-batch packed GT block; b and j are uniform -> compiler emits s_load,
    // keeping the whole inner loop off the LDS/VMEM pipes.
    const float* __restrict__ pb = prep + ((size_t)b << 9);   // b*64*8

    // ---- decode both anchors -> xyxy + wh ----
    float ax1[2], ay1[2], ax2[2], ay2[2], areaA[2], acx[2], acy[2], aw[2], ah[2];
    #pragma unroll
    for (int u = 0; u < 2; ++u) {
        const int a = a0 + u * A_HALF;
        int local, W, stride, bs;
        if (a < 36864)      { local = a;         W = 64; stride = 8;  bs = 32;  }
        else if (a < 46080) { local = a - 36864; W = 32; stride = 16; bs = 64;  }
        else if (a < 48384) { local = a - 46080; W = 16; stride = 32; bs = 128; }
        else                { local = a - 48384; W = 8;  stride = 64; bs = 256; }

        const int hw = local / 9;
        const int k  = local - hw * 9;
        const int y  = hw / W;
        const int x  = hw - y * W;
        const int r  = k / 3;
        const int s  = k - r * 3;

        // anchor w/h in double, exactly mirroring numpy's op order
        const double sc = (s == 0) ? 1.0 : ((s == 1) ? 1.2599210498948732
                                                     : 1.5874010519681994);
        const double rr = (r == 0) ? 0.5 : ((r == 1) ? 1.0 : 2.0);
        const double av   = (double)bs * sc;
        const double area = av * av;
        const double wd   = sqrt(area * rr);
        const double hd   = wd / rr;
        aw[u] = (float)wd; ah[u] = (float)hd;

        acx[u] = ((float)x + 0.5f) * (float)stride;
        acy[u] = ((float)y + 0.5f) * (float)stride;
        const float hx = aw[u] * 0.5f, hy = ah[u] * 0.5f;
        ax1[u] = acx[u] - hx; ay1[u] = acy[u] - hy;
        ax2[u] = acx[u] + hx; ay2[u] = acy[u] + hy;
        areaA[u] = (ax2[u] - ax1[u]) * (ay2[u] - ay1[u]);
    }

    // ---- division-free IoU argmax over 64 GT boxes, 2 anchors in flight ----
    // iou_j > iou_best <=> inter_j*den_best > inter_best*den_j (all dens > 0).
    // Strict '>' keeps first max (np.argmax). Init makes j=0 always win.
    float b_inter[2] = {-1.0f, -1.0f}, b_den[2] = {1.0f, 1.0f};
    int   bidx[2] = {0, 0};
    #pragma unroll 8
    for (int j = 0; j < M_GT; ++j) {
        const float gx = pb[j*8+0], gy = pb[j*8+1];
        const float gz = pb[j*8+2], gw = pb[j*8+3];
        const float ga = pb[j*8+4];
        #pragma unroll
        for (int u = 0; u < 2; ++u) {
            const float ltx = fmaxf(ax1[u], gx), lty = fmaxf(ay1[u], gy);
            const float rbx = fminf(ax2[u], gz), rby = fminf(ay2[u], gw);
            const float wx = fmaxf(rbx - ltx, 0.0f);
            const float wy = fmaxf(rby - lty, 0.0f);
            const float inter = wx * wy;
            const float den   = (areaA[u] + ga) - inter;   // same assoc as ref
            if (inter * b_den[u] > b_inter[u] * den) {
                b_inter[u] = inter; b_den[u] = den; bidx[u] = j;
            }
        }
    }

    // ---- epilogue: one divergent LDS gather per anchor ----
    #pragma unroll
    for (int u = 0; u < 2; ++u) {
        const float best = b_inter[u] / b_den[u];   // exact IEEE, matches ref bits

        float lab = slab[bidx[u]];
        if (best > 0.4f && best < 0.5f) lab = -1.0f;
        if (best < 0.4f)                lab = 0.0f;

        const float4 g = sbox[bidx[u]];
        const float gcx = (g.x + g.z) * 0.5f;
        const float gcy = (g.y + g.w) * 0.5f;
        const float tx = (gcx - acx[u]) / (aw[u] * 0.1f);
        const float ty = (gcy - acy[u]) / (ah[u] * 0.1f);
        const float tw = __logf((g.z - g.x) / aw[u]) * 5.0f;  // /0.2, tol ~4
        const float th = __logf((g.w - g.y) / ah[u]) * 5.0f;

        const size_t idx = (size_t)b * A_TOTAL + (a0 + u * A_HALF);
        ((float4*)out_loc)[idx] = make_float4(tx, ty, tw, th);
        out_cls[idx] = lab;
    }
}

extern "C" void kernel_launch(void* const* d_in, const int* in_sizes, int n_in,
                              void* d_out, int out_size, void* d_ws, size_t ws_size,
                              hipStream_t stream) {
    const float* gt_boxes  = (const float*)d_in[4];
    const int*   gt_labels = (const int*)d_in[5];

    float* prep    = (float*)d_ws;                                   // (B, 64, 8) = 32 KB
    float* out_loc = (float*)d_out;                                  // (B, A, 4)
    float* out_cls = (float*)d_out + (size_t)B_BATCH * A_TOTAL * 4;  // (B, A)

    prep_kernel<<<B_BATCH, 64, 0, stream>>>(gt_boxes, gt_labels, prep);

    dim3 grid((A_HALF + 255) / 256, B_BATCH);   // 96 x 16 blocks, 2 anchors/thread
    anchors_assign_kernel<<<grid, 256, 0, stream>>>(gt_boxes, gt_labels, prep,
                                                    out_loc, out_cls);
}

// Round 4
// 94.753 us; speedup vs baseline: 1.0998x; 1.0998x over previous
//
#include <hip/hip_runtime.h>
#include <math.h>

// Problem constants (from the reference):
//  levels: (64,64,s=8,bs=32) (32,32,s=16,bs=64) (16,16,s=32,bs=128) (8,8,s=64,bs=256)
//  K = 9 anchors/position (3 ratios x 3 scales), A = 48960, B = 16, M = 64 GT boxes
// Level boundaries 36864/46080/48384 are all multiples of 64 -> every wave is
// single-level, so per-wave bounding windows stay tight for pruning.
#define A_TOTAL 48960
#define M_GT    64
#define B_BATCH 16

__global__ __launch_bounds__(256) void anchors_assign_kernel(
    const float* __restrict__ gt_boxes,   // (B, 64, 4) xyxy
    const int*   __restrict__ gt_labels,  // (B, 64)
    float* __restrict__ out_loc,          // (B, A, 4)
    float* __restrict__ out_cls)          // (B, A)
{
    __shared__ float4 sbox[M_GT];
    __shared__ float  sarea[M_GT];
    __shared__ float  slab[M_GT];

    const int b   = blockIdx.y;
    const int tid = threadIdx.x;

    // Stage this batch's GT boxes into LDS (64 x float4 = 1 KiB)
    if (tid < M_GT) {
        float4 g = ((const float4*)gt_boxes)[b * M_GT + tid];
        sbox[tid]  = g;
        sarea[tid] = (g.z - g.x) * (g.w - g.y);   // same op order as ref
        slab[tid]  = (float)gt_labels[b * M_GT + tid];
    }
    __syncthreads();

    const int a = blockIdx.x * 256 + tid;
    if (a >= A_TOTAL) return;   // whole waves only (A_TOTAL % 64 == 0), after barrier

    // ---- decode anchor index -> level, position, k ----
    int local, W, stride, bs;
    if (a < 36864)      { local = a;         W = 64; stride = 8;  bs = 32;  }
    else if (a < 46080) { local = a - 36864; W = 32; stride = 16; bs = 64;  }
    else if (a < 48384) { local = a - 46080; W = 16; stride = 32; bs = 128; }
    else                { local = a - 48384; W = 8;  stride = 64; bs = 256; }

    const int hw = local / 9;
    const int k  = local - hw * 9;
    const int y  = hw / W;
    const int x  = hw - y * W;
    const int r  = k / 3;
    const int s  = k - r * 3;

    // ---- anchor w/h in double, exactly mirroring numpy's op order ----
    const double sc = (s == 0) ? 1.0 : ((s == 1) ? 1.2599210498948732   // 2^(1/3)
                                                 : 1.5874010519681994); // 2^(2/3)
    const double rr = (r == 0) ? 0.5 : ((r == 1) ? 1.0 : 2.0);
    const double av   = (double)bs * sc;
    const double area = av * av;
    const double wd   = sqrt(area * rr);
    const double hd   = wd / rr;
    const float aw = (float)wd, ah = (float)hd;

    const float acx = ((float)x + 0.5f) * (float)stride;
    const float acy = ((float)y + 0.5f) * (float)stride;
    const float hx = aw * 0.5f, hy = ah * 0.5f;
    const float ax1 = acx - hx, ay1 = acy - hy;
    const float ax2 = acx + hx, ay2 = acy + hy;
    const float areaA = (ax2 - ax1) * (ay2 - ay1);   // ref recomputes from xyxy

    // ---- per-wave bounding window (exact min/max butterfly over 64 lanes) ----
    float wx1 = ax1, wy1 = ay1, wx2 = ax2, wy2 = ay2;
    #pragma unroll
    for (int m = 1; m < 64; m <<= 1) {
        wx1 = fminf(wx1, __shfl_xor(wx1, m, 64));
        wy1 = fminf(wy1, __shfl_xor(wy1, m, 64));
        wx2 = fmaxf(wx2, __shfl_xor(wx2, m, 64));
        wy2 = fmaxf(wy2, __shfl_xor(wy2, m, 64));
    }

    // ---- candidate mask: lane j tests GT box j against the wave window ----
    // inter > 0 requires strict overlap; boxes only touching the window edge
    // have inter == 0 for every anchor in the wave -> safe to prune (a 0-iou
    // box can never be argmax given the b_inter=0 init below; the all-zero
    // case returns bidx=0, matching np.argmax).
    const int lane = tid & 63;
    const float4 gb = sbox[lane];
    const bool cand = (fminf(wx2, gb.z) > fmaxf(wx1, gb.x)) &&
                      (fminf(wy2, gb.w) > fmaxf(wy1, gb.y));
    unsigned long long mask = __ballot(cand);   // wave-uniform

    // ---- division-free IoU argmax over the candidate set (ascending j) ----
    // iou_j > iou_best <=> inter_j*den_best > inter_best*den_j (all dens > 0).
    // Strict '>' keeps the first max, matching np.argmax.
    float b_inter = 0.0f, b_den = 1.0f;
    int   bidx = 0;
    while (mask) {
        const int j = (int)__builtin_ctzll(mask);
        mask &= mask - 1;
        const float4 g = sbox[j];                // uniform j -> LDS broadcast
        const float ltx = fmaxf(ax1, g.x), lty = fmaxf(ay1, g.y);
        const float rbx = fminf(ax2, g.z), rby = fminf(ay2, g.w);
        const float wx = fmaxf(rbx - ltx, 0.0f);
        const float wy = fmaxf(rby - lty, 0.0f);
        const float inter = wx * wy;
        const float den   = (areaA + sarea[j]) - inter;   // same assoc as ref
        if (inter * b_den > b_inter * den) {
            b_inter = inter; b_den = den; bidx = j;
        }
    }
    const float best = b_inter / b_den;   // exact IEEE; 0/1 = 0 when no candidates

    // ---- label thresholding (order matches ref: ign first, bg overrides) ----
    float lab = slab[bidx];
    if (best > 0.4f && best < 0.5f) lab = -1.0f;
    if (best < 0.4f)                lab = 0.0f;

    // ---- box deltas from the argmax box ----
    const float4 g = sbox[bidx];
    const float gcx = (g.x + g.z) * 0.5f;
    const float gcy = (g.y + g.w) * 0.5f;
    const float tx = (gcx - acx) / (aw * 0.1f);
    const float ty = (gcy - acy) / (ah * 0.1f);
    const float tw = __logf((g.z - g.x) / aw) * 5.0f;   // /0.2 ; tol ~4
    const float th = __logf((g.w - g.y) / ah) * 5.0f;

    const size_t idx = (size_t)b * A_TOTAL + a;
    ((float4*)out_loc)[idx] = make_float4(tx, ty, tw, th);  // coalesced 16B store
    out_cls[idx] = lab;
}

extern "C" void kernel_launch(void* const* d_in, const int* in_sizes, int n_in,
                              void* d_out, int out_size, void* d_ws, size_t ws_size,
                              hipStream_t stream) {
    // inputs: f3, f4, f5, f6 (data unused; shapes are compile-time constants),
    //         gt_boxes (B,64,4) f32, gt_labels (B,64) int
    const float* gt_boxes  = (const float*)d_in[4];
    const int*   gt_labels = (const int*)d_in[5];

    float* out_loc = (float*)d_out;                                  // (B, A, 4)
    float* out_cls = (float*)d_out + (size_t)B_BATCH * A_TOTAL * 4;  // (B, A)

    dim3 grid((A_TOTAL + 255) / 256, B_BATCH);   // 192 x 16 blocks
    anchors_assign_kernel<<<grid, 256, 0, stream>>>(gt_boxes, gt_labels, out_loc, out_cls);
}

// Round 5
// 91.293 us; speedup vs baseline: 1.1415x; 1.0379x over previous
//
#include <hip/hip_runtime.h>
#include <math.h>

// Problem constants (from the reference):
//  levels: (64,64,s=8,bs=32) (32,32,s=16,bs=64) (16,16,s=32,bs=128) (8,8,s=64,bs=256)
//  K = 9 anchors/position (3 ratios x 3 scales), A = 48960, B = 16, M = 64 GT boxes
// Level boundaries 36864/46080/48384 are multiples of 64 -> every wave is
// single-level, windows stay tight. Wave w covers anchors [64w, 64w+64) in
// BOTH kernels, so prep's per-wave windows transfer exactly.
#define A_TOTAL 48960
#define N_WAVES (A_TOTAL / 64)   // 765
#define M_GT    64
#define B_BATCH 16

// ---- prep: batch-invariant per-anchor + per-wave data, computed once ----
// rec[a]  = {acx, acy, aw, ah}                       (anchor center + wh, f64-exact cast)
// rin[a]  = {1/(aw*0.1), 1/(ah*0.1), 1/aw, 1/ah}     (epilogue reciprocals)
// win[w]  = {wx1, wy1, wx2, wy2}                     (wave bounding window, exact)
__global__ __launch_bounds__(256) void prep_kernel(
    float4* __restrict__ rec, float4* __restrict__ rin, float4* __restrict__ win)
{
    const int a = blockIdx.x * 256 + threadIdx.x;
    if (a >= A_TOTAL) return;   // whole waves only (boundary % 64 == 0)

    int local, W, stride, bs;
    if (a < 36864)      { local = a;         W = 64; stride = 8;  bs = 32;  }
    else if (a < 46080) { local = a - 36864; W = 32; stride = 16; bs = 64;  }
    else if (a < 48384) { local = a - 46080; W = 16; stride = 32; bs = 128; }
    else                { local = a - 48384; W = 8;  stride = 64; bs = 256; }

    const int hw = local / 9;
    const int k  = local - hw * 9;
    const int y  = hw / W;
    const int x  = hw - y * W;
    const int r  = k / 3;
    const int s  = k - r * 3;

    // anchor w/h in double, exactly mirroring numpy's op order:
    // a = bs*scale; area = a*a; w = sqrt(area*rr); h = w/rr; cast f32
    const double sc = (s == 0) ? 1.0 : ((s == 1) ? 1.2599210498948732   // 2^(1/3)
                                                 : 1.5874010519681994); // 2^(2/3)
    const double rr = (r == 0) ? 0.5 : ((r == 1) ? 1.0 : 2.0);
    const double av   = (double)bs * sc;
    const double area = av * av;
    const double wd   = sqrt(area * rr);
    const double hd   = wd / rr;
    const float aw = (float)wd, ah = (float)hd;

    const float acx = ((float)x + 0.5f) * (float)stride;
    const float acy = ((float)y + 0.5f) * (float)stride;
    const float hx = aw * 0.5f, hy = ah * 0.5f;      // exact (*2^-1)
    const float ax1 = acx - hx, ay1 = acy - hy;
    const float ax2 = acx + hx, ay2 = acy + hy;

    rec[a] = make_float4(acx, acy, aw, ah);
    rin[a] = make_float4(1.0f / (aw * 0.1f), 1.0f / (ah * 0.1f),
                         1.0f / aw,          1.0f / ah);

    // per-wave bounding window (exact min/max butterfly over 64 lanes)
    float wx1 = ax1, wy1 = ay1, wx2 = ax2, wy2 = ay2;
    #pragma unroll
    for (int m = 1; m < 64; m <<= 1) {
        wx1 = fminf(wx1, __shfl_xor(wx1, m, 64));
        wy1 = fminf(wy1, __shfl_xor(wy1, m, 64));
        wx2 = fmaxf(wx2, __shfl_xor(wx2, m, 64));
        wy2 = fmaxf(wy2, __shfl_xor(wy2, m, 64));
    }
    if ((threadIdx.x & 63) == 0) win[a >> 6] = make_float4(wx1, wy1, wx2, wy2);
}

__global__ __launch_bounds__(256) void anchors_assign_kernel(
    const float*  __restrict__ gt_boxes,   // (B, 64, 4) xyxy
    const int*    __restrict__ gt_labels,  // (B, 64)
    const float4* __restrict__ rec,        // per-anchor {acx,acy,aw,ah}
    const float4* __restrict__ rin,        // per-anchor reciprocals
    const float4* __restrict__ win,        // per-wave window
    float* __restrict__ out_loc,           // (B, A, 4)
    float* __restrict__ out_cls)           // (B, A)
{
    __shared__ float4 sbox[M_GT];
    __shared__ float  sarea[M_GT];
    __shared__ float  slab[M_GT];

    const int b   = blockIdx.y;
    const int tid = threadIdx.x;

    if (tid < M_GT) {
        float4 g = ((const float4*)gt_boxes)[b * M_GT + tid];
        sbox[tid]  = g;
        sarea[tid] = (g.z - g.x) * (g.w - g.y);   // same op order as ref
        slab[tid]  = (float)gt_labels[b * M_GT + tid];
    }
    __syncthreads();

    const int a = blockIdx.x * 256 + tid;
    if (a >= A_TOTAL) return;

    // batch-invariant anchor data (L2-resident, coalesced float4 loads)
    const float4 rc = rec[a];
    const float4 ri = rin[a];
    const float4 wv = win[a >> 6];          // same address across the wave -> 1 line

    const float acx = rc.x, acy = rc.y, aw = rc.z, ah = rc.w;
    const float hx = aw * 0.5f, hy = ah * 0.5f;    // bit-identical reconstruction
    const float ax1 = acx - hx, ay1 = acy - hy;
    const float ax2 = acx + hx, ay2 = acy + hy;
    const float areaA = (ax2 - ax1) * (ay2 - ay1); // ref recomputes from xyxy

    // candidate mask: lane j tests GT box j against the wave window.
    // Edge-touching boxes have inter==0 for every anchor in the wave -> safe
    // to prune (0-iou can't win vs b_inter=0 init; all-zero case -> bidx=0 = np.argmax).
    const int lane = tid & 63;
    const float4 gb = sbox[lane];
    const bool cand = (fminf(wv.z, gb.z) > fmaxf(wv.x, gb.x)) &&
                      (fminf(wv.w, gb.w) > fmaxf(wv.y, gb.y));
    unsigned long long mask = __ballot(cand);   // wave-uniform

    // division-free IoU argmax over candidates, ascending j (keeps first max).
    float b_inter = 0.0f, b_den = 1.0f;
    int   bidx = 0;
    while (mask) {
        const int j = (int)__builtin_ctzll(mask);
        mask &= mask - 1;
        const float4 g = sbox[j];               // uniform j -> LDS broadcast
        const float ltx = fmaxf(ax1, g.x), lty = fmaxf(ay1, g.y);
        const float rbx = fminf(ax2, g.z), rby = fminf(ay2, g.w);
        const float wx = fmaxf(rbx - ltx, 0.0f);
        const float wy = fmaxf(rby - lty, 0.0f);
        const float inter = wx * wy;
        const float den   = (areaA + sarea[j]) - inter;   // same assoc as ref
        if (inter * b_den > b_inter * den) {
            b_inter = inter; b_den = den; bidx = j;
        }
    }
    const float best = b_inter / b_den;   // exact IEEE: bit-matches ref's iou

    // label thresholding (order matches ref: ign first, bg overrides)
    float lab = slab[bidx];
    if (best > 0.4f && best < 0.5f) lab = -1.0f;
    if (best < 0.4f)                lab = 0.0f;

    // box deltas from the argmax box (reciprocal muls; tol 3.92 >> 2-ulp error)
    const float4 g = sbox[bidx];
    const float gcx = (g.x + g.z) * 0.5f;
    const float gcy = (g.y + g.w) * 0.5f;
    const float tx = (gcx - acx) * ri.x;
    const float ty = (gcy - acy) * ri.y;
    const float tw = __logf((g.z - g.x) * ri.z) * 5.0f;   // /0.2
    const float th = __logf((g.w - g.y) * ri.w) * 5.0f;

    const size_t idx = (size_t)b * A_TOTAL + a;
    ((float4*)out_loc)[idx] = make_float4(tx, ty, tw, th);  // coalesced 16B store
    out_cls[idx] = lab;
}

extern "C" void kernel_launch(void* const* d_in, const int* in_sizes, int n_in,
                              void* d_out, int out_size, void* d_ws, size_t ws_size,
                              hipStream_t stream) {
    // inputs: f3..f6 (data unused; shapes compile-time), gt_boxes f32, gt_labels int
    const float* gt_boxes  = (const float*)d_in[4];
    const int*   gt_labels = (const int*)d_in[5];

    // d_ws layout (re-poisoned each call; prep rewrites it every call):
    float4* rec = (float4*)d_ws;                    // 48960 * 16 B
    float4* rin = rec + A_TOTAL;                    // 48960 * 16 B
    float4* win = rin + A_TOTAL;                    // 765   * 16 B  (~1.58 MB total)

    float* out_loc = (float*)d_out;                                  // (B, A, 4)
    float* out_cls = (float*)d_out + (size_t)B_BATCH * A_TOTAL * 4;  // (B, A)

    prep_kernel<<<(A_TOTAL + 255) / 256, 256, 0, stream>>>(rec, rin, win);

    dim3 grid((A_TOTAL + 255) / 256, B_BATCH);   // 192 x 16 blocks
    anchors_assign_kernel<<<grid, 256, 0, stream>>>(gt_boxes, gt_labels,
                                                    rec, rin, win, out_loc, out_cls);
}